// Round 10
// baseline (135.350 us; speedup 1.0000x reference)
//
#include <hip/hip_runtime.h>
#include <hip/hip_bf16.h>
#include <cstdint>
#include <math.h>

#define S_LEN 2048
#define D_DIM 512
#define NROWS 8192           // B*S
#define NQKV  1536           // 3*512 output cols of the fused projection
#define QK_SCALE 0.04419417382415922f   // 1/sqrt(512)

typedef unsigned short u16;
typedef unsigned long long u64;
typedef __attribute__((ext_vector_type(8))) short short8;
typedef __attribute__((ext_vector_type(4))) float floatx4;

__device__ inline floatx4 mfma16(short8 a, short8 b, floatx4 c){
  return __builtin_amdgcn_mfma_f32_16x16x32_bf16(a, b, c, 0, 0, 0);
}
__device__ inline u16 f2b(float f){
  uint32_t u = __float_as_uint(f);
  u = (u + 0x7fffu + ((u >> 16) & 1u)) >> 16;
  return (u16)u;
}
__device__ inline float b2f(u16 u){ return __uint_as_float(((uint32_t)u) << 16); }
#define GLD16(g, l) __builtin_amdgcn_global_load_lds( \
    (const __attribute__((address_space(1))) void*)(g), \
    (__attribute__((address_space(3))) void*)(l), 16, 0, 0)

// ---------------------------------------------------------------- convert
__global__ void cvt_kernel(const float* __restrict__ x,
                           const float* __restrict__ Wq,
                           const float* __restrict__ Wk,
                           const float* __restrict__ Wv,
                           u16* __restrict__ xw)
{
  const int NT4 = (NROWS * D_DIM) / 4 + (NQKV * D_DIM) / 4;
  for (int i = blockIdx.x * blockDim.x + threadIdx.x; i < NT4;
       i += gridDim.x * blockDim.x) {
    int e = i * 4;
    const float* src;
    if (e < NROWS * D_DIM) {
      src = x + e;
    } else {
      int j = e - NROWS * D_DIM;
      if (j < 512 * 512)           src = Wq + j;
      else if (j < 2 * 512 * 512)  src = Wk + (j - 512 * 512);
      else                         src = Wv + (j - 2 * 512 * 512);
    }
    float4 v = *(const float4*)src;
    ushort4 o;
    o.x = f2b(v.x); o.y = f2b(v.y); o.z = f2b(v.z); o.w = f2b(v.w);
    *(ushort4*)(xw + e) = o;
  }
}

// ---------------------------------------------------------------- QKV GEMM
__launch_bounds__(256)
__global__ void qkv_gemm(const u16* __restrict__ xb,
                         const u16* __restrict__ wb,
                         const float* __restrict__ bq,
                         const float* __restrict__ bk,
                         const float* __restrict__ bv,
                         u16* __restrict__ qb,
                         u16* __restrict__ kb,
                         u16* __restrict__ vt)
{
  __shared__ alignas(16) u16 sm[2][16384];   // [buf][ A 128x64 | B 128x64 ]
  const int tid = threadIdx.x;
  const int l = tid & 63, w = tid >> 6;
  const int lr = l & 15, lg = l >> 4;
  const int wr = w >> 1, wc = w & 1;
  const int bid = blockIdx.x;
  const int xcd = bid & 7;
  const int t = bid >> 3;              // 0..95
  const int bn = t % 12, bmhi = t / 12;
  const int bm = (bmhi << 3) | xcd;    // A-panel pinned to XCD bm&7
  const int m0 = bm * 128, n0 = bn * 128;

  const u16* gA = xb + (size_t)(m0 + (tid >> 3)) * D_DIM + (tid & 7) * 8;
  const u16* gB = wb + (size_t)(n0 + (tid >> 3)) * D_DIM + (tid & 7) * 8;

#define STAGEK(BUF, KT) { \
  char* la = (char*)&sm[BUF][0] + tid * 16; \
  char* lb = (char*)&sm[BUF][8192] + tid * 16; \
  const u16* ga = gA + (KT) * 64; \
  const u16* gb = gB + (KT) * 64; \
  _Pragma("unroll") for (int jj = 0; jj < 4; jj++) { \
    GLD16(ga + (size_t)jj * 32 * D_DIM, la + jj * 4096); \
    GLD16(gb + (size_t)jj * 32 * D_DIM, lb + jj * 4096); } }

  floatx4 acc[4][4];
#pragma unroll
  for (int m = 0; m < 4; m++)
#pragma unroll
    for (int n = 0; n < 4; n++) acc[m][n] = 0.0f;

  STAGEK(0, 0)
  __syncthreads();

  for (int kt = 0; kt < 8; ++kt) {
    const int cb = kt & 1;
    if (kt < 7) STAGEK(cb ^ 1, kt + 1)
#pragma unroll
    for (int kk = 0; kk < 2; ++kk) {
      short8 a[4], bfr[4];
#pragma unroll
      for (int m = 0; m < 4; m++)
        a[m] = *(const short8*)&sm[cb][(wr * 64 + m * 16 + lr) * 64 + kk * 32 + lg * 8];
#pragma unroll
      for (int n = 0; n < 4; n++)
        bfr[n] = *(const short8*)&sm[cb][8192 + (wc * 64 + n * 16 + lr) * 64 + kk * 32 + lg * 8];
#pragma unroll
      for (int m = 0; m < 4; m++)
#pragma unroll
        for (int n = 0; n < 4; n++)
          acc[m][n] = mfma16(a[m], bfr[n], acc[m][n]);
    }
    __syncthreads();
  }
#undef STAGEK

  if (n0 < 1024) {
    const float* bias = (n0 < 512) ? bq : bk;
    u16* dst = (n0 < 512) ? qb : kb;
    const float scl = (n0 < 512) ? QK_SCALE : 1.0f;
    const int nbase = n0 & 511;
#pragma unroll
    for (int n = 0; n < 4; n++) {
      int gn = nbase + wc * 64 + n * 16 + lr;
      float bia = bias[gn];
#pragma unroll
      for (int m = 0; m < 4; m++) {
        int gm0 = m0 + wr * 64 + m * 16 + lg * 4;
#pragma unroll
        for (int r = 0; r < 4; r++)
          dst[(size_t)(gm0 + r) * D_DIM + gn] = f2b((acc[m][n][r] + bia) * scl);
      }
    }
  } else {
    const int nbase = n0 - 1024;
    const int bIdx = m0 >> 11;
    const int s0 = m0 & 2047;
    __syncthreads();
#pragma unroll
    for (int h = 0; h < 2; ++h) {
      if (wc == h) {
#pragma unroll
        for (int n = 0; n < 4; n++) {
          int lrow = n * 16 + lr;
          float bia = bv[nbase + h * 64 + lrow];
#pragma unroll
          for (int m = 0; m < 4; m++) {
            int lcol = wr * 64 + m * 16 + lg * 4;
#pragma unroll
            for (int r = 0; r < 4; r++)
              sm[0][lrow * 136 + lcol + r] = f2b(acc[m][n][r] + bia);
          }
        }
      }
      __syncthreads();
      {
        int row = tid >> 2;
        int c0 = (tid & 3) * 32;
        u16* dstp = vt + (size_t)bIdx * D_DIM * S_LEN
                       + (size_t)(nbase + h * 64 + row) * S_LEN + s0 + c0;
        const u16* srcp = &sm[0][row * 136 + c0];
#pragma unroll
        for (int jj = 0; jj < 4; jj++)
          *(short8*)(dstp + jj * 8) = *(const short8*)(srcp + jj * 8);
      }
      __syncthreads();
    }
  }
}

// ---------------------------------------------------------------- attention
// Per block (b, qt: 64 q-rows, chunk c: 128 kv). 4 waves, 256 thr.
// Phase1 (GEMM1): S^T[128kv][64q] = K.Q^T, D=512 contraction, 8 dbuf'd
//   LDS k-steps (m97 structure). Wave w owns kv-slice w*32.
// Phase2: exp+causal-mask in-register; P[64q][128kv] bf16 -> swizzled LDS;
//   rsum via 2 shfls + 1KB LDS.
// Phase3 (GEMM2): O[64q][512d] = P.V, V^T frags from L2. Wave w owns d-slice.
// LDS 66560 B -> 2 blocks/CU. Grid 1088: nch(qt)=qt/2+1, slot=b*272+j.
__launch_bounds__(256)
__global__ void attn_chunk(const u16* __restrict__ qb,
                           const u16* __restrict__ kb,
                           const u16* __restrict__ vt,
                           u16* __restrict__ pOb,
                           float* __restrict__ pR)
{
  extern __shared__ char smem[];
  // K0 @0 (16K) | K1 @16384 | Q0 @32768 (8K) | Q1 @40960 | P @49152 (16K) | rsumx @65536 (1K)

  const int bid = blockIdx.x;
  const int xcd = bid & 7;
  const int b = xcd >> 1;
  const int j = (bid >> 3) * 2 + (xcd & 1);   // 0..271 within batch
  // invert j -> (qt, c): cum(2m)=m(m+1), cum(2m+1)=(m+1)^2
  int m = (int)(sqrtf((float)j + 0.25f) - 0.5f + 1e-4f);
  if (m * (m + 1) > j) --m;
  else if ((m + 1) * (m + 2) <= j) ++m;
  int qt, c;
  if (j < (m + 1) * (m + 1)) { qt = 2 * m;     c = j - m * (m + 1); }
  else                       { qt = 2 * m + 1; c = j - (m + 1) * (m + 1); }
  const int slot = b * 272 + j;

  const int tid = threadIdx.x;
  const int w = tid >> 6, l = tid & 63;
  const int lr = l & 15, lg = l >> 4;
  const int swz = (lr & 7) << 4;

  const u16* qsrc = qb + ((size_t)(b * S_LEN + qt * 64)) * D_DIM;
  const u16* ksrc = kb + ((size_t)(b * S_LEN + c * 128)) * D_DIM;

  // stage K[128][64] + Q[64][64] for k-step ks into buf (pre-swizzled source)
  auto stage = [&](int buf, int ks) {
#pragma unroll
    for (int i = 0; i < 4; ++i) {
      const int bo = tid * 16 + i * 4096;
      const int row = bo >> 7, colb = bo & 127;
      GLD16(ksrc + (size_t)row * D_DIM + ks * 64 + (((colb) ^ ((row & 7) << 4)) >> 1),
            smem + buf * 16384 + bo);
    }
#pragma unroll
    for (int i = 0; i < 2; ++i) {
      const int bo = tid * 16 + i * 4096;
      const int row = bo >> 7, colb = bo & 127;
      GLD16(qsrc + (size_t)row * D_DIM + ks * 64 + (((colb) ^ ((row & 7) << 4)) >> 1),
            smem + 32768 + buf * 8192 + bo);
    }
  };

  // ---------------- GEMM1: S^T[128kv][64q], wave kv-slice = w*32
  floatx4 acc1[2][4];
#pragma unroll
  for (int tk = 0; tk < 2; ++tk)
#pragma unroll
    for (int tq = 0; tq < 4; ++tq) acc1[tk][tq] = 0.0f;

  stage(0, 0);
  __syncthreads();
  for (int ks = 0; ks < 8; ++ks) {
    const int cb = ks & 1;
    if (ks < 7) stage(cb ^ 1, ks + 1);
    char* Kl = smem + cb * 16384;
    char* Ql = smem + 32768 + cb * 8192;
#pragma unroll
    for (int kk = 0; kk < 2; ++kk) {
      short8 kf[2], qf[4];
#pragma unroll
      for (int tk = 0; tk < 2; ++tk) {
        const int row = w * 32 + tk * 16 + lr;
        kf[tk] = *(const short8*)(Kl + row * 128 + ((kk * 64 + lg * 16) ^ swz));
      }
#pragma unroll
      for (int tq = 0; tq < 4; ++tq) {
        const int row = tq * 16 + lr;
        qf[tq] = *(const short8*)(Ql + row * 128 + ((kk * 64 + lg * 16) ^ swz));
      }
#pragma unroll
      for (int tk = 0; tk < 2; ++tk)
#pragma unroll
        for (int tq = 0; tq < 4; ++tq)
          acc1[tk][tq] = mfma16(kf[tk], qf[tq], acc1[tk][tq]);
    }
    __syncthreads();
  }

  // ---------------- Phase2: exp + mask -> P (LDS, swizzled), rsum partials
  {
    char* Pl = smem + 49152;
    float rs4[4] = {0.f, 0.f, 0.f, 0.f};
    const int q0 = qt * 64;
    const int kvb = c * 128 + w * 32;
#pragma unroll
    for (int tk = 0; tk < 2; ++tk)
#pragma unroll
      for (int tq = 0; tq < 4; ++tq) {
        const int qg = q0 + tq * 16 + lr;
        const int kvg = kvb + tk * 16 + lg * 4;
        float p0 = (kvg + 0 <= qg) ? __expf(acc1[tk][tq][0]) : 0.f;
        float p1 = (kvg + 1 <= qg) ? __expf(acc1[tk][tq][1]) : 0.f;
        float p2 = (kvg + 2 <= qg) ? __expf(acc1[tk][tq][2]) : 0.f;
        float p3 = (kvg + 3 <= qg) ? __expf(acc1[tk][tq][3]) : 0.f;
        ushort4 pk;
        pk.x = f2b(p0); pk.y = f2b(p1); pk.z = f2b(p2); pk.w = f2b(p3);
        rs4[tq] += b2f(pk.x) + b2f(pk.y) + b2f(pk.z) + b2f(pk.w);
        *(ushort4*)(Pl + (tq * 16 + lr) * 256 + (((w * 32 + tk * 16 + lg * 4) * 2) ^ swz)) = pk;
      }
#pragma unroll
    for (int tq = 0; tq < 4; ++tq) {
      rs4[tq] += __shfl_xor(rs4[tq], 16);
      rs4[tq] += __shfl_xor(rs4[tq], 32);
    }
    if (lg == 0) {
      float* rx = (float*)(smem + 65536);
#pragma unroll
      for (int tq = 0; tq < 4; ++tq) rx[w * 64 + tq * 16 + lr] = rs4[tq];
    }
  }
  __syncthreads();

  // ---------------- GEMM2: O[64q][512d] = P.V, wave d-slice = w*128
  floatx4 acc2[4][8];
#pragma unroll
  for (int tq = 0; tq < 4; ++tq)
#pragma unroll
    for (int td = 0; td < 8; ++td) acc2[tq][td] = 0.0f;

  {
    char* Pl = smem + 49152;
    const u16* vsrc = vt + (size_t)b * D_DIM * S_LEN
                         + (size_t)(w * 128) * S_LEN + c * 128;
#pragma unroll
    for (int ks = 0; ks < 4; ++ks) {
      short8 pf[4], vf[8];
#pragma unroll
      for (int td = 0; td < 8; ++td)
        vf[td] = *(const short8*)(vsrc + (size_t)(td * 16 + lr) * S_LEN + ks * 32 + lg * 8);
#pragma unroll
      for (int tq = 0; tq < 4; ++tq)
        pf[tq] = *(const short8*)(Pl + (tq * 16 + lr) * 256 + ((ks * 64 + lg * 16) ^ swz));
#pragma unroll
      for (int tq = 0; tq < 4; ++tq)
#pragma unroll
        for (int td = 0; td < 8; ++td)
          acc2[tq][td] = mfma16(pf[tq], vf[td], acc2[tq][td]);
    }
  }

  // ---------------- flush partials
  {
    u16* po = pOb + (size_t)slot * (64 * 512) + w * 128;
#pragma unroll
    for (int tq = 0; tq < 4; ++tq)
#pragma unroll
      for (int r = 0; r < 4; ++r) {
        const int row = tq * 16 + lg * 4 + r;
        u16* op = po + (size_t)row * 512 + lr;
#pragma unroll
        for (int td = 0; td < 8; ++td)
          __builtin_nontemporal_store(f2b(acc2[tq][td][r]), op + td * 16);
      }
    if (tid < 64) {
      const float* rx = (const float*)(smem + 65536);
      float rs = rx[tid] + rx[64 + tid] + rx[128 + tid] + rx[192 + tid];
      __builtin_nontemporal_store(rs, &pR[slot * 64 + tid]);
    }
  }
}

// ---------------------------------------------------------------- reduce partials
__launch_bounds__(256)
__global__ void attn_reduce(const u16* __restrict__ pOb,
                            const float* __restrict__ pR,
                            float* __restrict__ out)
{
  const int id = blockIdx.x;            // b(2) | qt(5) | quarter(2): 512 blocks
  const int b = id >> 7;
  const int qt = (id >> 2) & 31;
  const int qu = id & 3;
  const int h = qt >> 1;
  const int nch = h + 1;
  const int base = b * 272 + (h + 1) * (h + (qt & 1));   // b*272 + cum(qt)

  const int row = threadIdx.x >> 2;                 // 0..63
  const int c0 = qu * 128 + (threadIdx.x & 3) * 32; // col start

  float rs = 0.f;
  for (int c = 0; c < nch; ++c) rs += pR[(base + c) * 64 + row];
  const float inv = 1.0f / rs;

  float acc[32];
#pragma unroll
  for (int e = 0; e < 32; ++e) acc[e] = 0.f;
  for (int c = 0; c < nch; ++c) {
    const u16* src = pOb + ((size_t)(base + c) * 64 + row) * 512 + c0;
#pragma unroll
    for (int t = 0; t < 8; ++t) {
      ushort4 v = ((const ushort4*)src)[t];
      acc[t * 4 + 0] += b2f(v.x);
      acc[t * 4 + 1] += b2f(v.y);
      acc[t * 4 + 2] += b2f(v.z);
      acc[t * 4 + 3] += b2f(v.w);
    }
  }
  float* dst = out + ((size_t)(b * S_LEN + qt * 64 + row)) * 512 + c0;
#pragma unroll
  for (int t = 0; t < 8; ++t) {
    float4 v;
    v.x = acc[t * 4 + 0] * inv;
    v.y = acc[t * 4 + 1] * inv;
    v.z = acc[t * 4 + 2] * inv;
    v.w = acc[t * 4 + 3] * inv;
    *(float4*)(dst + t * 4) = v;
  }
}

// ---------------------------------------------------------------- launch
extern "C" void kernel_launch(void* const* d_in, const int* in_sizes, int n_in,
                              void* d_out, int out_size, void* d_ws, size_t ws_size,
                              hipStream_t stream)
{
  const float* x  = (const float*)d_in[0];
  const float* Wq = (const float*)d_in[1];
  const float* bq = (const float*)d_in[2];
  const float* Wk = (const float*)d_in[3];
  const float* bk = (const float*)d_in[4];
  const float* Wv = (const float*)d_in[5];
  const float* bv = (const float*)d_in[6];
  float* out = (float*)d_out;

  u16* xw = (u16*)d_ws;
  u16* xb = xw;                              // [8192][512] bf16
  u16* wb = xb + (size_t)NROWS * D_DIM;      // [1536][512] bf16
  u16* qb = wb + (size_t)NQKV * D_DIM;       // [8192][512] bf16 (scaled)
  u16* kb = qb + (size_t)NROWS * D_DIM;      // [8192][512] bf16
  u16* vt = kb + (size_t)NROWS * D_DIM;      // [4][512][2048] bf16 (V^T)
  u16* pOb = vt + (size_t)NROWS * D_DIM;     // [1088][64][512] bf16 partial numerators
  float* pR = (float*)(pOb + (size_t)1088 * 64 * D_DIM);  // [1088][64] f32

  hipLaunchKernelGGL(cvt_kernel, dim3(2048), dim3(256), 0, stream, x, Wq, Wk, Wv, xw);
  hipLaunchKernelGGL(qkv_gemm, dim3(768), dim3(256), 0, stream,
                     xb, wb, bq, bk, bv, qb, kb, vt);
  hipLaunchKernelGGL(attn_chunk, dim3(1088), dim3(256), 66560, stream,
                     qb, kb, vt, pOb, pR);
  hipLaunchKernelGGL(attn_reduce, dim3(512), dim3(256), 0, stream, pOb, pR, out);
}